// Round 5
// baseline (415.134 us; speedup 1.0000x reference)
//
#include <hip/hip_runtime.h>

#define N_NODES 100000
#define N_EDGES 1600000
#define IN_DIM 128
#define OUT_DIM 32

#define BKT_ROWS 64
#define NBKT 1563                 // ceil(100000/64)
#define GRP_BKTS 24
#define GRP_ROWS 1536             // 24*64
#define NGRP 66                   // ceil(1563/24)
#define EPB 4096
#define BINA_BLOCKS ((N_EDGES + EPB - 1) / EPB)   // 391
#define BINB_CPG 8                                // chunk-stride per group

// -------- kernel 1: support = X @ W (proven; unchanged) --------
__global__ __launch_bounds__(256) void gemm_support(
    const float* __restrict__ x, const float* __restrict__ w,
    float* __restrict__ support) {
  __shared__ float ws[IN_DIM][OUT_DIM];
  __shared__ float xs[8][IN_DIM];
  const int tid = threadIdx.x;

  for (int i = tid; i < IN_DIM * OUT_DIM; i += 256)
    ws[i / OUT_DIM][i % OUT_DIM] = w[i];

  const int row0 = blockIdx.x * 8;
  for (int i = tid; i < 8 * IN_DIM; i += 256) {
    const int r = i / IN_DIM, k = i % IN_DIM;
    const int row = row0 + r;
    xs[r][k] = (row < N_NODES) ? x[(long long)row * IN_DIM + k] : 0.f;
  }
  __syncthreads();

  const int r = tid >> 5;
  const int c = tid & 31;
  const int row = row0 + r;
  if (row >= N_NODES) return;

  float acc = 0.f;
#pragma unroll
  for (int k = 0; k < IN_DIM; ++k)
    acc = fmaf(xs[r][k], ws[k][c], acc);
  support[(long long)row * OUT_DIM + c] = acc;
}

// -------- kernel 2: bucket histogram (1563 buckets, LDS pre-agg) --------
__global__ __launch_bounds__(256) void hist_all(
    const int* __restrict__ rows, int* __restrict__ gHist) {
  __shared__ int h[NBKT];
  const int t = threadIdx.x;
  for (int b = t; b < NBKT; b += 256) h[b] = 0;
  __syncthreads();
  const long long stride = (long long)gridDim.x * 256;
  for (long long e = (long long)blockIdx.x * 256 + t; e < N_EDGES; e += stride)
    atomicAdd(&h[rows[e] >> 6], 1);
  __syncthreads();
  for (int b = t; b < NBKT; b += 256)
    if (h[b]) atomicAdd(&gHist[b], h[b]);
}

// -------- kernel 3: scan of 1563 bucket counts (one block, 2/thread) -------
__global__ __launch_bounds__(1024) void scan_all(
    const int* __restrict__ gHist, int* __restrict__ segB,
    int* __restrict__ gCurA, int* __restrict__ gCurB) {
  __shared__ int sm[1024];
  const int t = threadIdx.x;
  const int i0 = 2 * t, i1 = 2 * t + 1;
  const int a = (i0 < NBKT) ? gHist[i0] : 0;
  const int b = (i1 < NBKT) ? gHist[i1] : 0;
  const int s = a + b;
  sm[t] = s;
  __syncthreads();
  for (int off = 1; off < 1024; off <<= 1) {
    int v = (t >= off) ? sm[t - off] : 0;
    __syncthreads();
    sm[t] += v;
    __syncthreads();
  }
  const int excl = sm[t] - s;
  if (i0 < NBKT) { segB[i0] = excl;     gCurB[i0] = excl; }
  if (i1 < NBKT) { segB[i1] = excl + a; gCurB[i1] = excl + a; }
  if (t == 1023) segB[NBKT] = sm[t];
  // group-level cursors: exclusive prefix at element 24*g == sm[12g-1]
  if (t < NGRP) gCurA[t] = (t == 0) ? 0 : sm[12 * t - 1];
}

// -------- kernel 4: pass A — bin edges into 66 groups (coalesced flush) ----
__global__ __launch_bounds__(256) void binA(
    const int* __restrict__ rows, const int* __restrict__ cols,
    const float* __restrict__ vals, int* __restrict__ gCurA,
    unsigned long long* __restrict__ gKV1) {
  __shared__ unsigned long long kvS[EPB];   // 32 KB
  __shared__ unsigned char gOf[EPB];        // 4 KB
  __shared__ int hist[NGRP], base[NGRP], cursor[NGRP], gb[NGRP];
  const int t = threadIdx.x;
  const long long b0 = (long long)blockIdx.x * EPB;
  const int n = (int)min((long long)EPB, (long long)N_EDGES - b0);

  if (t < NGRP) hist[t] = 0;
  __syncthreads();

  for (int k = 0; k < EPB / 256; ++k) {
    const int j = k * 256 + t;
    if (j < n) atomicAdd(&hist[rows[b0 + j] / GRP_ROWS], 1);
  }
  __syncthreads();
  if (t == 0) {
    int s = 0;
    for (int g = 0; g < NGRP; ++g) { base[g] = s; cursor[g] = s; s += hist[g]; }
  }
  __syncthreads();

  for (int k = 0; k < EPB / 256; ++k) {
    const int j = k * 256 + t;
    if (j < n) {
      const long long e = b0 + j;
      const int r = rows[e];
      const int g = r / GRP_ROWS;
      const unsigned key = ((unsigned)(r - g * GRP_ROWS) << 17) | (unsigned)cols[e];
      const unsigned long long kv =
          ((unsigned long long)__float_as_uint(vals[e]) << 32) | key;
      const int pos = atomicAdd(&cursor[g], 1);
      kvS[pos] = kv;
      gOf[pos] = (unsigned char)g;
    }
  }
  __syncthreads();

  if (t < NGRP) {
    const int cnt = hist[t];
    gb[t] = (cnt > 0) ? atomicAdd(&gCurA[t], cnt) : 0;
  }
  __syncthreads();

  for (int i = t; i < n; i += 256) {
    const int g = gOf[i];
    gKV1[(long long)gb[g] + (i - base[g])] = kvS[i];
  }
}

// -------- kernel 5: pass B — bin each group into its 24 buckets ------------
__global__ __launch_bounds__(256) void binB(
    const int* __restrict__ segB, int* __restrict__ gCurB,
    const unsigned long long* __restrict__ gKV1,
    unsigned long long* __restrict__ gKV2) {
  __shared__ unsigned long long kvS[EPB];   // 32 KB
  __shared__ unsigned char bOf[EPB];        // 4 KB
  __shared__ int hist[GRP_BKTS], base[GRP_BKTS], cursor[GRP_BKTS], gb[GRP_BKTS];
  const int t = threadIdx.x;
  const int g = blockIdx.x >> 3;            // /BINB_CPG
  const int c0 = blockIdx.x & (BINB_CPG - 1);
  if (g >= NGRP) return;
  const int b0k = 24 * g;
  const int gs = segB[b0k];
  const int ge = segB[(24 * (g + 1) < NBKT) ? 24 * (g + 1) : NBKT];

  for (int c = c0; gs + c * EPB < ge; c += BINB_CPG) {
    const int cbase = gs + c * EPB;
    const int n = min(EPB, ge - cbase);

    if (t < GRP_BKTS) hist[t] = 0;
    __syncthreads();

    for (int k = 0; k < EPB / 256; ++k) {
      const int j = k * 256 + t;
      if (j < n) {
        const unsigned key = (unsigned)gKV1[cbase + j];
        atomicAdd(&hist[(key >> 17) >> 6], 1);   // bucket-local = row_local/64
      }
    }
    __syncthreads();
    if (t == 0) {
      int s = 0;
      for (int b = 0; b < GRP_BKTS; ++b) { base[b] = s; cursor[b] = s; s += hist[b]; }
    }
    __syncthreads();

    for (int k = 0; k < EPB / 256; ++k) {
      const int j = k * 256 + t;
      if (j < n) {
        const unsigned long long kv = gKV1[cbase + j];
        const int bl = ((unsigned)kv >> 17) >> 6;
        const int pos = atomicAdd(&cursor[bl], 1);
        kvS[pos] = kv;
        bOf[pos] = (unsigned char)bl;
      }
    }
    __syncthreads();

    if (t < GRP_BKTS) {
      const int cnt = hist[t];
      gb[t] = (cnt > 0) ? atomicAdd(&gCurB[b0k + t], cnt) : 0;
    }
    __syncthreads();

    for (int i = t; i < n; i += 256) {
      const int bl = bOf[i];
      gKV2[(long long)gb[bl] + (i - base[bl])] = kvS[i];
    }
    __syncthreads();
  }
}

// -------- kernel 6: per-bucket LDS-dense SpMM, zero global atomics ---------
__global__ __launch_bounds__(256) void spmm64(
    const int* __restrict__ segB, const unsigned long long* __restrict__ gKV2,
    const float* __restrict__ support, const float* __restrict__ bias,
    float* __restrict__ out) {
  __shared__ float accum[BKT_ROWS * OUT_DIM];        // 8 KB
  __shared__ unsigned long long kvL[1024];           // 8 KB
  const int t = threadIdx.x;
  const int B = blockIdx.x;
  const int s = segB[B];
  const int e = segB[B + 1];

  for (int j = t; j < BKT_ROWS * OUT_DIM; j += 256) accum[j] = 0.f;

  const int u = t >> 5;      // unit 0..7
  const int d = t & 31;      // output dim

  for (int base = s; base < e; base += 1024) {
    const int n = min(1024, e - base);
    __syncthreads();
    for (int j = t; j < n; j += 256) kvL[j] = gKV2[base + j];
    __syncthreads();

    int j = u;
    for (; j + 24 < n; j += 32) {
      const unsigned long long k0 = kvL[j];
      const unsigned long long k1 = kvL[j + 8];
      const unsigned long long k2 = kvL[j + 16];
      const unsigned long long k3 = kvL[j + 24];
      const int c0 = (int)((unsigned)k0 & 0x1FFFFu);
      const int c1 = (int)((unsigned)k1 & 0x1FFFFu);
      const int c2 = (int)((unsigned)k2 & 0x1FFFFu);
      const int c3 = (int)((unsigned)k3 & 0x1FFFFu);
      const float s0 = support[c0 * OUT_DIM + d];
      const float s1 = support[c1 * OUT_DIM + d];
      const float s2 = support[c2 * OUT_DIM + d];
      const float s3 = support[c3 * OUT_DIM + d];
      const int r0 = (int)(((unsigned)k0 >> 17) & 63u);
      const int r1 = (int)(((unsigned)k1 >> 17) & 63u);
      const int r2 = (int)(((unsigned)k2 >> 17) & 63u);
      const int r3 = (int)(((unsigned)k3 >> 17) & 63u);
      atomicAdd(&accum[r0 * OUT_DIM + d], __uint_as_float((unsigned)(k0 >> 32)) * s0);
      atomicAdd(&accum[r1 * OUT_DIM + d], __uint_as_float((unsigned)(k1 >> 32)) * s1);
      atomicAdd(&accum[r2 * OUT_DIM + d], __uint_as_float((unsigned)(k2 >> 32)) * s2);
      atomicAdd(&accum[r3 * OUT_DIM + d], __uint_as_float((unsigned)(k3 >> 32)) * s3);
    }
    for (; j < n; j += 8) {
      const unsigned long long kv = kvL[j];
      const int c = (int)((unsigned)kv & 0x1FFFFu);
      const int rl = (int)(((unsigned)kv >> 17) & 63u);
      const float v = __uint_as_float((unsigned)(kv >> 32));
      atomicAdd(&accum[rl * OUT_DIM + d], v * support[c * OUT_DIM + d]);
    }
  }
  __syncthreads();

  const int row0 = B * BKT_ROWS;
  for (int j = t; j < BKT_ROWS * OUT_DIM; j += 256) {
    const int row = row0 + (j >> 5);
    if (row < N_NODES) out[(long long)row * OUT_DIM + (j & 31)] = accum[j] + bias[j & 31];
  }
}

extern "C" void kernel_launch(void* const* d_in, const int* in_sizes, int n_in,
                              void* d_out, int out_size, void* d_ws, size_t ws_size,
                              hipStream_t stream) {
  const float* x        = (const float*)d_in[0];
  const int*   adj_rows = (const int*)d_in[1];
  const int*   adj_cols = (const int*)d_in[2];
  const float* adj_vals = (const float*)d_in[3];
  const float* weight   = (const float*)d_in[4];
  const float* bias     = (const float*)d_in[5];
  float* out = (float*)d_out;

  // ---- workspace layout (~25.62 MB; bufA reused: gKV1 then support) ----
  char* wsp = (char*)d_ws;
  unsigned long long* gKV1 = (unsigned long long*)wsp;              // 12.8 MB
  float* support = (float*)wsp;                                     // aliases gKV1
  unsigned long long* gKV2 = (unsigned long long*)(wsp + 12800000); // 12.8 MB
  int* segB  = (int*)(wsp + 25600000);        // 1564 ints
  int* gHist = segB + 1600;                   // 1563 ints
  int* gCurA = gHist + 1600;                  // 66 ints (pad 128)
  int* gCurB = gCurA + 128;                   // 1563 ints

  hipMemsetAsync(gHist, 0, NBKT * sizeof(int), stream);

  hist_all<<<256, 256, 0, stream>>>(adj_rows, gHist);
  scan_all<<<1, 1024, 0, stream>>>(gHist, segB, gCurA, gCurB);
  binA<<<BINA_BLOCKS, 256, 0, stream>>>(adj_rows, adj_cols, adj_vals, gCurA, gKV1);
  binB<<<NGRP * BINB_CPG, 256, 0, stream>>>(segB, gCurB, gKV1, gKV2);
  // gemm AFTER binB: support overwrites the gKV1 buffer
  gemm_support<<<(N_NODES + 7) / 8, 256, 0, stream>>>(x, weight, support);
  spmm64<<<NBKT, 256, 0, stream>>>(segB, gKV2, support, bias, out);
}

// Round 6
// 147.264 us; speedup vs baseline: 2.8190x; 2.8190x over previous
//
#include <hip/hip_runtime.h>

#define N_NODES 100000
#define N_EDGES 1600000
#define IN_DIM 128
#define OUT_DIM 32

typedef _Float16 h2 __attribute__((ext_vector_type(2)));

// -------- kernel 1: support = X @ W (proven; unchanged) --------
__global__ __launch_bounds__(256) void gemm_support(
    const float* __restrict__ x, const float* __restrict__ w,
    float* __restrict__ support) {
  __shared__ float ws[IN_DIM][OUT_DIM];
  __shared__ float xs[8][IN_DIM];
  const int tid = threadIdx.x;

  for (int i = tid; i < IN_DIM * OUT_DIM; i += 256)
    ws[i / OUT_DIM][i % OUT_DIM] = w[i];

  const int row0 = blockIdx.x * 8;
  for (int i = tid; i < 8 * IN_DIM; i += 256) {
    const int r = i / IN_DIM, k = i % IN_DIM;
    const int row = row0 + r;
    xs[r][k] = (row < N_NODES) ? x[(long long)row * IN_DIM + k] : 0.f;
  }
  __syncthreads();

  const int r = tid >> 5;
  const int c = tid & 31;
  const int row = row0 + r;
  if (row >= N_NODES) return;

  float acc = 0.f;
#pragma unroll
  for (int k = 0; k < IN_DIM; ++k)
    acc = fmaf(xs[r][k], ws[k][c], acc);
  support[(long long)row * OUT_DIM + c] = acc;
}

// -------- packed v2f16 atomic add (HW fadd; CAS fallback) --------
__device__ __forceinline__ void pk_atomic_add_h2(h2* p, h2 v) {
#if __has_builtin(__builtin_amdgcn_global_atomic_fadd_v2f16)
  __builtin_amdgcn_global_atomic_fadd_v2f16(
      (__attribute__((address_space(1))) h2*)p, v);
#else
  unsigned* pu = (unsigned*)p;
  unsigned old = *pu;
  while (true) {
    h2 cur = __builtin_bit_cast(h2, old);
    h2 nv = cur + v;
    unsigned n = __builtin_bit_cast(unsigned, nv);
    unsigned r = atomicCAS(pu, old, n);
    if (r == old) break;
    old = r;
  }
#endif
}

// -------- kernel 2: edge-parallel scatter with packed fp16 atomics ---------
// 16 lanes per edge, 2 dims per lane: 25.6M 4B atomics (half of R1's bytes).
__global__ __launch_bounds__(256) void scatter_h2(
    const int* __restrict__ rows, const int* __restrict__ cols,
    const float* __restrict__ vals, const float* __restrict__ support,
    h2* __restrict__ out_h) {
  const long long gid = (long long)blockIdx.x * 256 + threadIdx.x;
  if (gid >= (long long)N_EDGES * 16) return;
  const int e = (int)(gid >> 4);
  const int l = (int)(gid & 15);          // pair index 0..15
  const int r = rows[e];
  const int c = cols[e];
  const float v = vals[e];
  const float2 s = *(const float2*)(support + (long long)c * OUT_DIM + 2 * l);
  h2 inc = { (_Float16)(v * s.x), (_Float16)(v * s.y) };
  pk_atomic_add_h2(out_h + (long long)r * 16 + l, inc);
}

// -------- kernel 3: finalize out = fp32(out_h) + bias ----------------------
// 8 halves per thread (16B read, 32B write).
__global__ __launch_bounds__(256) void finalize_h(
    const h2* __restrict__ out_h, const float* __restrict__ bias,
    float* __restrict__ out) {
  const int i = blockIdx.x * 256 + threadIdx.x;     // 8-elem group index
  if (i >= N_NODES * OUT_DIM / 8) return;
  const h2* src = out_h + i * 4;
  float4 a, b;
  h2 p0 = src[0], p1 = src[1], p2 = src[2], p3 = src[3];
  const int d0 = (i * 8) & 31;                      // dims d0..d0+7
  a.x = (float)p0[0] + bias[d0 + 0];
  a.y = (float)p0[1] + bias[d0 + 1];
  a.z = (float)p1[0] + bias[d0 + 2];
  a.w = (float)p1[1] + bias[d0 + 3];
  b.x = (float)p2[0] + bias[d0 + 4];
  b.y = (float)p2[1] + bias[d0 + 5];
  b.z = (float)p3[0] + bias[d0 + 6];
  b.w = (float)p3[1] + bias[d0 + 7];
  float4* dst = (float4*)(out + (long long)i * 8);
  dst[0] = a;
  dst[1] = b;
}

extern "C" void kernel_launch(void* const* d_in, const int* in_sizes, int n_in,
                              void* d_out, int out_size, void* d_ws, size_t ws_size,
                              hipStream_t stream) {
  const float* x        = (const float*)d_in[0];
  const int*   adj_rows = (const int*)d_in[1];
  const int*   adj_cols = (const int*)d_in[2];
  const float* adj_vals = (const float*)d_in[3];
  const float* weight   = (const float*)d_in[4];
  const float* bias     = (const float*)d_in[5];
  float* out = (float*)d_out;

  // ---- workspace: support fp32 (12.8 MB) + out_h fp16 (6.4 MB) ----
  char* wsp = (char*)d_ws;
  float* support = (float*)wsp;                     // 12,800,000 B
  h2* out_h = (h2*)(wsp + 12800000);                // 6,400,000 B

  hipMemsetAsync(out_h, 0, (size_t)N_NODES * OUT_DIM * sizeof(_Float16),
                 stream);
  gemm_support<<<(N_NODES + 7) / 8, 256, 0, stream>>>(x, weight, support);

  {
    const long long total = (long long)N_EDGES * 16;
    scatter_h2<<<(int)((total + 255) / 256), 256, 0, stream>>>(
        adj_rows, adj_cols, adj_vals, support, out_h);
  }
  {
    const int total = N_NODES * OUT_DIM / 8;
    finalize_h<<<(total + 255) / 256, 256, 0, stream>>>(out_h, bias, out);
  }
}